// Round 18
// baseline (2827.134 us; speedup 1.0000x reference)
//
#include <hip/hip_runtime.h>
#include <stdint.h>

typedef __attribute__((ext_vector_type(8))) short short8;
typedef __attribute__((ext_vector_type(16))) float floatx16;

#define PLANE16 8388608  // 8*256*256*16 elems: one 16-channel plane

__device__ __forceinline__ float b2f(short s) {
  union { uint32_t u; float f; } v; v.u = ((uint32_t)(uint16_t)s) << 16; return v.f;
}
__device__ __forceinline__ short f2b(float f) {
  union { float f; uint32_t u; } v; v.f = f;
  uint32_t r = (v.u + 0x7FFFu + ((v.u >> 16) & 1u)) >> 16;
  return (short)r;
}

// ---------------------------------------------------------------------------
// Main MFMA conv: 3x3, pad 1, C_in = 16*NC16 (chunks 0-3 = planes of in1,
// 4-7 = planes of in2), C_out = 64, PReLU.
// Activations: 16-ch planes NHWC bf16 [4][8][256][256][16].
//
// ROUND-18: NO LDS, NO BARRIERS. Per-block A-working-set is 3 rows x 256 px
// x 32 B ~ 25 KB (L1-scale) and the whole tensor is L2-resident (FETCH at
// ideal since r8) -- staging cache-fit data was pure overhead (guide m169:
// dropping such staging was +26%). Each lane loads its 16-B A-fragment
// per tap directly from global (bounds-checked pad); waves are fully
// independent -- the collective barrier stalls that bounded every staged
// variant at ~114 us are structurally gone. 9x tap re-read is L1/L2-served
// (~600 MB/conv @ ~34 TB/s ~ 18 us, affordable).
//
// SESSION LAWS (hardware-verified):
//  - 1024-thr blocks force 64 VGPR -> spill; (512,2) safe; WRITE_SIZE>65.5MB
//    = spill canary. (r3/5/6)
//  - Write addressing naively; the compiler hoists (manual factoring
//    regressed every time: r7/r9/r11).
//  - XCD-affine decode: b = wgid&7 keeps halo + producer->consumer L2-local.
//
// A-frag k-map (k = 8*(l>>5)+e, cin = c16*16+k) and B-pack share the same
// permutation (cancels).
// C/D: col(=cout_local)=lane&31, row(=px_local)=(r&3)+8*(r>>2)+4*(lane>>5)
// ---------------------------------------------------------------------------
template<int NC16>
__global__ __launch_bounds__(512, 2)
void k_conv(const short* __restrict__ in1, const short* __restrict__ in2,
            const short* __restrict__ wp, const float* __restrict__ bias,
            const float* __restrict__ alpha, short* __restrict__ out)
{
  const int wg = blockIdx.x;          // 0..2047
  const int b = wg & 7;               // = XCD id under linear round-robin
  const int y = wg >> 3;              // consecutive y rows share an XCD
  const int tid = threadIdx.x;
  const int l = tid & 63;
  const int w = tid >> 6;             // wave = px tile (0..7)
  const int lm = l & 31;
  const int lh = l >> 5;

  floatx16 acc[2];  // [nblk]
  #pragma unroll
  for (int nb = 0; nb < 2; ++nb)
    #pragma unroll
    for (int r = 0; r < 16; ++r) acc[nb][r] = 0.f;

  #pragma unroll
  for (int c16 = 0; c16 < NC16; ++c16) {
    const short* __restrict__ src =
        ((c16 < 4) ? in1 : in2) + (size_t)(c16 & 3) * PLANE16;

    #pragma unroll
    for (int ky = 0; ky < 3; ++ky) {
      const int yy = y + ky - 1;
      const bool rowok = (unsigned)yy < 256u;
      #pragma unroll
      for (int kx = 0; kx < 3; ++kx) {
        const int ks = c16 * 9 + ky * 3 + kx;
        const short8 bw0 = *(const short8*)(wp + ((ks * 2 + 0) * 64 + l) * 8);
        const short8 bw1 = *(const short8*)(wp + ((ks * 2 + 1) * 64 + l) * 8);
        const int xx = w * 32 + lm + kx - 1;
        short8 av = {0, 0, 0, 0, 0, 0, 0, 0};
        if (rowok && (unsigned)xx < 256u)
          av = *(const short8*)(src + ((b * 256 + yy) * 256 + xx) * 16 + lh * 8);
        acc[0] = __builtin_amdgcn_mfma_f32_32x32x16_bf16(av, bw0, acc[0], 0, 0, 0);
        acc[1] = __builtin_amdgcn_mfma_f32_32x32x16_bf16(av, bw1, acc[1], 0, 0, 0);
      }
    }
  }

  const float alp = alpha[0];
  #pragma unroll
  for (int nb = 0; nb < 2; ++nb) {
    const float bs = bias[nb * 32 + lm];
    short* __restrict__ op = out + (size_t)(nb * 2 + (lm >> 4)) * PLANE16 + (lm & 15);
    #pragma unroll
    for (int r = 0; r < 16; ++r) {
      int px = w * 32 + (r & 3) + ((r >> 2) << 3) + (lh << 2);
      float v = acc[nb][r] + bs;
      v = v >= 0.f ? v : alp * v;
      op[((b * 256 + y) * 256 + px) * 16] = f2b(v);
    }
  }
}

// ---------------------------------------------------------------------------
// Weight pre-pack, c16-major (ks16 = c16*9 + tap).
// element (ks16, nblk, lane, e) =
//   W[cout = nblk*32 + lane&31][cin = c16*16 + 8*(lane>>5) + e][ky][kx]
// ---------------------------------------------------------------------------
__global__ __launch_bounds__(256)
void k_pack(const float* __restrict__ w2, const float* __restrict__ w3,
            const float* __restrict__ w4, const float* __restrict__ wf,
            short* __restrict__ wp234, short* __restrict__ wpfus)
{
  int idx = blockIdx.x * 256 + threadIdx.x;
  if (idx < 24 * 36864) {
    int conv = idx / 36864;
    int r = idx - conv * 36864;
    int which = conv >> 3, g = conv & 7;
    const float* W = (which == 0 ? w2 : which == 1 ? w3 : w4) + g * 36864;
    int ks = r >> 10;                 // [0,36) = c16*9 + t
    int nblk = (r >> 9) & 1;
    int lane = (r >> 3) & 63;
    int e = r & 7;
    int c16 = ks / 9;
    int t = ks - c16 * 9;
    int cin = c16 * 16 + ((lane >> 5) << 3) + e;
    int cout = nblk * 32 + (lane & 31);
    int ky = t / 3, kx = t % 3;
    wp234[idx] = f2b(W[((cout * 64 + cin) * 3 + ky) * 3 + kx]);
  } else {
    int idx2 = idx - 24 * 36864;
    if (idx2 >= 7 * 73728) return;
    int conv = idx2 / 73728;
    int r = idx2 - conv * 73728;
    const float* W = wf + conv * 73728;
    int ks = r >> 10;                 // [0,72)
    int nblk = (r >> 9) & 1;
    int lane = (r >> 3) & 63;
    int e = r & 7;
    int c16 = ks / 9;
    int t = ks - c16 * 9;
    int cin = c16 * 16 + ((lane >> 5) << 3) + e;
    int cout = nblk * 32 + (lane & 31);
    int ky = t / 3, kx = t % 3;
    wpfus[idx2] = f2b(W[((cout * 128 + cin) * 3 + ky) * 3 + kx]);
  }
}

// ---------------------------------------------------------------------------
// Head stage 1: sample conv (32x32, stride 32). s_all[g][b][c][gy][gx], fp32.
// ---------------------------------------------------------------------------
__global__ __launch_bounds__(256)
void k_sample(const float* __restrict__ x, const float* __restrict__ sw,
              float* __restrict__ s_all)
{
  int idx = blockIdx.x * 256 + threadIdx.x;  // 8*8*13*64 = 53248 threads
  int gx = idx & 7, gy = (idx >> 3) & 7;
  int t = idx >> 6;
  int c = t % 13; t /= 13;
  int b = t & 7, g = t >> 3;
  const float* xb = x + b * 65536 + (gy * 32) * 256 + gx * 32;
  const float* wp = sw + (g * 13 + c) * 1024;
  float acc = 0.f;
  for (int i = 0; i < 32; ++i) {
    #pragma unroll
    for (int j = 0; j < 32; ++j) acc += xb[i * 256 + j] * wp[i * 32 + j];
  }
  s_all[idx] = acc;
}

// ---------------------------------------------------------------------------
// Head stage 2: 1x1 up conv + bias, fused with depth_to_space.
// z_all[g][b][y][x] fp32, pos = (y%32)*32 + (x%32).
// ---------------------------------------------------------------------------
__global__ __launch_bounds__(256)
void k_upz(const float* __restrict__ s_all, const float* __restrict__ upw,
           const float* __restrict__ upb, float* __restrict__ z_all)
{
  int idx = blockIdx.x * 256 + threadIdx.x;  // 4194304
  int x = idx & 255, y = (idx >> 8) & 255;
  int b = (idx >> 16) & 7, g = idx >> 19;
  int pos = (y & 31) * 32 + (x & 31);
  int gy = y >> 5, gx = x >> 5;
  const float* sp = s_all + ((g * 8 + b) * 13) * 64 + gy * 8 + gx;
  const float* wp = upw + (g * 1024 + pos) * 13;
  float a = upb[g * 1024 + pos];
  #pragma unroll
  for (int c = 0; c < 13; ++c) a += wp[c] * sp[c * 64];
  z_all[idx] = a;
}

// ---------------------------------------------------------------------------
// Head stage 3: conv1 (1 -> 64, 3x3, pad 1) + PReLU, writes 16-ch planes.
// XCD-affine: b = wgid & 7 so its writes land on the XCD that fus will read.
// ---------------------------------------------------------------------------
__global__ __launch_bounds__(256)
void k_conv1(const float* __restrict__ z, const float* __restrict__ w,
             const float* __restrict__ bias, const float* __restrict__ alpha,
             short* __restrict__ out)
{
  int wg = blockIdx.x;                 // 0..2047
  int b = wg & 7;
  int y = wg >> 3;                     // 0..255
  int x = threadIdx.x;                 // 0..255
  int pid = (b * 256 + y) * 256 + x;
  float zv[9];
  #pragma unroll
  for (int t = 0; t < 9; ++t) {
    int dy = t / 3, dx = t % 3;
    int yy = y + dy - 1, xx = x + dx - 1;
    zv[t] = ((unsigned)yy < 256u && (unsigned)xx < 256u)
              ? z[b * 65536 + yy * 256 + xx] : 0.f;
  }
  float alp = alpha[0];
  #pragma unroll
  for (int c0 = 0; c0 < 64; c0 += 8) {
    short8 pack;
    #pragma unroll
    for (int e = 0; e < 8; ++e) {
      int c = c0 + e;
      float a = bias[c];
      #pragma unroll
      for (int t = 0; t < 9; ++t) a += w[c * 9 + t] * zv[t];
      a = a >= 0.f ? a : alp * a;
      pack[e] = f2b(a);
    }
    *(short8*)(out + (size_t)(c0 >> 4) * PLANE16 + pid * 16 + (c0 & 8)) = pack;
  }
}

// ---------------------------------------------------------------------------
// t5: 64 -> 1, 3x3, pad 1, + bias, fp32 output into d_out slice.
// XCD-affine b = wgid & 7: reads act produced on the same XCD.
// ---------------------------------------------------------------------------
__global__ __launch_bounds__(256)
void k_t5(const short* __restrict__ in, const float* __restrict__ w,
          const float* __restrict__ bias, float* __restrict__ out)
{
  int wg = blockIdx.x;                 // 0..2047
  int b = wg & 7;
  int y = wg >> 3;                     // 0..255
  int x = threadIdx.x;                 // 0..255
  float acc = bias[0];
  for (int dy = 0; dy < 3; ++dy) {
    int yy = y + dy - 1;
    if ((unsigned)yy >= 256u) continue;
    for (int dx = 0; dx < 3; ++dx) {
      int xx = x + dx - 1;
      if ((unsigned)xx >= 256u) continue;
      const int pix = (b * 256 + yy) * 256 + xx;
      #pragma unroll
      for (int c0 = 0; c0 < 64; c0 += 8) {
        short8 v = *(const short8*)(in + (size_t)(c0 >> 4) * PLANE16 + pix * 16 + (c0 & 8));
        #pragma unroll
        for (int e = 0; e < 8; ++e)
          acc += w[(c0 + e) * 9 + dy * 3 + dx] * b2f(v[e]);
      }
    }
  }
  out[(b * 256 + y) * 256 + x] = acc;
}

// ---------------------------------------------------------------------------
extern "C" void kernel_launch(void* const* d_in, const int* in_sizes, int n_in,
                              void* d_out, int out_size, void* d_ws, size_t ws_size,
                              hipStream_t stream) {
  const float* X   = (const float*)d_in[0];
  const float* SW  = (const float*)d_in[1];
  const float* UPW = (const float*)d_in[2];
  const float* UPB = (const float*)d_in[3];
  const float* C1W = (const float*)d_in[4];
  const float* C1B = (const float*)d_in[5];
  const float* C1A = (const float*)d_in[6];
  const float* FW  = (const float*)d_in[7];
  const float* FB  = (const float*)d_in[8];
  const float* FA  = (const float*)d_in[9];
  const float* W2  = (const float*)d_in[10];
  const float* B2  = (const float*)d_in[11];
  const float* A2  = (const float*)d_in[12];
  const float* W3  = (const float*)d_in[13];
  const float* B3  = (const float*)d_in[14];
  const float* A3  = (const float*)d_in[15];
  const float* W4  = (const float*)d_in[16];
  const float* B4  = (const float*)d_in[17];
  const float* A4  = (const float*)d_in[18];
  const float* W5  = (const float*)d_in[19];
  const float* B5  = (const float*)d_in[20];
  float* OUT = (float*)d_out;
  (void)in_sizes; (void)n_in; (void)out_size; (void)ws_size;

  uint8_t* base = (uint8_t*)d_ws;
  size_t off = 0;
  auto alloc = [&](size_t bytes) -> uint8_t* {
    uint8_t* r = base + off;
    off += (bytes + 255) & ~(size_t)255;
    return r;
  };
  const size_t ACT_ELEMS = 4ull * PLANE16;             // 33,554,432 bf16
  short* act[3];
  for (int i = 0; i < 3; ++i) act[i] = (short*)alloc(ACT_ELEMS * 2);
  float* z_all = (float*)alloc(4194304ull * 4);
  float* s_all = (float*)alloc(53248ull * 4);
  short* wp234 = (short*)alloc(884736ull * 2);
  short* wpfus = (short*)alloc(516096ull * 2);

  k_pack<<<dim3(5472), dim3(256), 0, stream>>>(W2, W3, W4, FW, wp234, wpfus);
  k_sample<<<dim3(208), dim3(256), 0, stream>>>(X, SW, s_all);
  k_upz<<<dim3(16384), dim3(256), 0, stream>>>(s_all, UPW, UPB, z_all);

  int cur = 0, A = 1, B = 2;
  // head(0) -> cur
  k_conv1<<<dim3(2048), dim3(256), 0, stream>>>(z_all, C1W, C1B, C1A, act[cur]);

  for (int m = 0; m < 8; ++m) {
    const short* wp_t2 = wp234 + (0 * 8 + m) * 36864;
    const short* wp_t3 = wp234 + (1 * 8 + m) * 36864;
    const short* wp_t4 = wp234 + (2 * 8 + m) * 36864;

    k_conv<4><<<dim3(2048), dim3(512), 0, stream>>>(
        act[cur], act[cur], wp_t2, B2 + m * 64, A2 + m, act[A]);
    k_conv<4><<<dim3(2048), dim3(512), 0, stream>>>(
        act[A], act[A], wp_t3, B3 + m * 64, A3 + m, act[B]);
    k_conv<4><<<dim3(2048), dim3(512), 0, stream>>>(
        act[B], act[B], wp_t4, B4 + m * 64, A4 + m, act[A]);
    k_t5<<<dim3(2048), dim3(256), 0, stream>>>(
        act[A], W5 + m * 576, B5 + m, OUT + (size_t)m * 524288);

    if (m < 7) {
      // head(m+1) -> act[B] (free after t4 consumed it)
      k_conv1<<<dim3(2048), dim3(256), 0, stream>>>(
          z_all + (size_t)(m + 1) * 524288, C1W + (m + 1) * 576,
          C1B + (m + 1) * 64, C1A + (m + 1), act[B]);
      // fus(cur, head) -> act[A] (free after t5 consumed it)
      k_conv<8><<<dim3(2048), dim3(512), 0, stream>>>(
          act[cur], act[B], wpfus + m * 73728, FB + m * 64, FA + m, act[A]);
      int tmp = cur; cur = A; A = tmp;  // new cur = fus output
    }
  }
}

// Round 19
// 2685.444 us; speedup vs baseline: 1.0528x; 1.0528x over previous
//
#include <hip/hip_runtime.h>
#include <stdint.h>

typedef __attribute__((ext_vector_type(8))) short short8;
typedef __attribute__((ext_vector_type(16))) float floatx16;

#define PLANE16 8388608  // 8*256*256*16 elems: one 16-channel plane
#define LDSBUF 24768     // 3*258*32 bytes: one 16-ch chunk tile

__device__ __forceinline__ float b2f(short s) {
  union { uint32_t u; float f; } v; v.u = ((uint32_t)(uint16_t)s) << 16; return v.f;
}
__device__ __forceinline__ short f2b(float f) {
  union { float f; uint32_t u; } v; v.f = f;
  uint32_t r = (v.u + 0x7FFFu + ((v.u >> 16) & 1u)) >> 16;
  return (short)r;
}

// LDS tile: [buf][3 rows][258 xp][16 ch] bf16, 32 B per (r,xp) row. Swizzle
// XORs only byte bit 4 (16-B half within the row) with xp2^xp3^xp4 ->
// injective half-swap (validated R10/R16); same fn on write & read.
// buf index is compile-time-constant under the unrolled chunk loop.
__device__ __forceinline__ uint32_t ldsA(int buf, int r, int xp, int c) {
  uint32_t byte = (uint32_t)buf * LDSBUF
                + ((uint32_t)(r * 258 + xp) << 5) + ((uint32_t)c << 1);
  byte ^= (uint32_t)((((xp >> 2) ^ (xp >> 3) ^ (xp >> 4)) & 1) << 4);
  return byte;
}

// ---------------------------------------------------------------------------
// Main MFMA conv: 3x3, pad 1, C_in = 16*NC16 (chunks 0-3 = planes of in1,
// 4-7 = planes of in2), C_out = 64, PReLU.
// Activations: 16-ch planes NHWC bf16 [4][8][256][256][16].
// Structure: 1-row block, 8 waves, wave w owns px tile w, 18 MFMA/chunk.
// Two LDS buffers (2 x 24.8 KB -> 3 blocks/CU) -> ONE barrier per chunk:
// compute from buf[c&1], commit into buf[(c+1)&1], sync.
//
// SESSION-FINAL (r19 = r17 verbatim; best verified 2650 us). Search summary:
//  - staged + async-issue beats direct-global (r18: latency exposure +7%)
//  - and beats more-barriers (r16) / deeper pipelining (r10, compiler-fragile)
//  - XCD-affine decode +9% (r8/r13); setprio -7% t-conv (r14)
//  - occupancy ladder 2->3->4 blocks/CU -6%/-8% (r15/r16)
//  - do not rewrite inner-loop addressing exprs (r7/r9/r11)
//  - (512,2) launch bounds; WRITE_SIZE > 65.5 MB = spill canary (r3/5/6)
//
// A-frag k-map (k = 8*(l>>5)+e, cin = c16*16+k) and B-pack share the same
// permutation (cancels).
// C/D: col(=cout_local)=lane&31, row(=px_local)=(r&3)+8*(r>>2)+4*(lane>>5)
// ---------------------------------------------------------------------------
template<int NC16>
__global__ __launch_bounds__(512, 2)
void k_conv(const short* __restrict__ in1, const short* __restrict__ in2,
            const short* __restrict__ wp, const float* __restrict__ bias,
            const float* __restrict__ alpha, short* __restrict__ out)
{
  __shared__ __align__(16) uint8_t smem[2 * LDSBUF];
  const int wg = blockIdx.x;          // 0..2047
  const int b = wg & 7;               // = XCD id under linear round-robin
  const int y = wg >> 3;              // consecutive y rows share an XCD
  const int tid = threadIdx.x;
  const int l = tid & 63;
  const int w = tid >> 6;             // wave = px tile (0..7)
  const int lm = l & 31;
  const int lh = l >> 5;

  floatx16 acc[2];  // [nblk]
  #pragma unroll
  for (int nb = 0; nb < 2; ++nb)
    #pragma unroll
    for (int r = 0; r < 16; ++r) acc[nb][r] = 0.f;

  const int xbase = w * 32 + lm;

  // staging: widx = tid + i*512 in [0,1536): r = widx>>9, xp = ((widx&511)>>1)+1,
  // half = widx&1. Exactly 3 16-B items/thread.
  short8 stg[3];

  auto issue = [&](int c16) {
    const short* __restrict__ src =
        ((c16 < 4) ? in1 : in2) + (size_t)(c16 & 3) * PLANE16;
    #pragma unroll
    for (int i = 0; i < 3; ++i) {
      int widx = tid + i * 512;
      int r = widx >> 9;
      int rem = widx & 511;
      int xp = (rem >> 1) + 1;
      int half = rem & 1;
      int yy = y + r - 1;
      short8 v = {0, 0, 0, 0, 0, 0, 0, 0};
      if ((unsigned)yy < 256u)
        v = *(const short8*)(src + ((b * 256 + yy) * 256 + (xp - 1)) * 16 + half * 8);
      stg[i] = v;
    }
  };
  auto commit = [&](int buf) {
    #pragma unroll
    for (int i = 0; i < 3; ++i) {
      int widx = tid + i * 512;
      int r = widx >> 9;
      int rem = widx & 511;
      int xp = (rem >> 1) + 1;
      int half = rem & 1;
      *(short8*)(smem + ldsA(buf, r, xp, half * 8)) = stg[i];
    }
  };

  // zero the constant x-pad columns (xp=0, 257) of BOTH buffers once; chunk
  // commits never touch these bytes (ldsA is injective within the row).
  if (tid < 24) {
    short8 z = {0, 0, 0, 0, 0, 0, 0, 0};
    int buf = tid / 12;
    int t12 = tid - buf * 12;
    int r = t12 >> 2;
    int xp = (t12 & 2) ? 257 : 0;
    int half = t12 & 1;
    *(short8*)(smem + ldsA(buf, r, xp, half * 8)) = z;
  }

  issue(0);
  commit(0);
  __syncthreads();

  #pragma unroll
  for (int c16 = 0; c16 < NC16; ++c16) {
    const int p = c16 & 1;
    if (c16 + 1 < NC16) issue(c16 + 1);   // loads fly under the MFMA phase

    __builtin_amdgcn_s_setprio(1);        // T5: favor MFMA waves over other
                                          // resident blocks' staging
    #pragma unroll
    for (int ky = 0; ky < 3; ++ky)
    #pragma unroll
    for (int kx = 0; kx < 3; ++kx) {
      const int ks = c16 * 9 + ky * 3 + kx;
      const short8 bw0 = *(const short8*)(wp + ((ks * 2 + 0) * 64 + l) * 8);
      const short8 bw1 = *(const short8*)(wp + ((ks * 2 + 1) * 64 + l) * 8);
      const int cl = lh * 8;
      const int xp = xbase + kx;
      const short8 av = *(const short8*)(smem + ldsA(p, ky, xp, cl));
      acc[0] = __builtin_amdgcn_mfma_f32_32x32x16_bf16(av, bw0, acc[0], 0, 0, 0);
      acc[1] = __builtin_amdgcn_mfma_f32_32x32x16_bf16(av, bw1, acc[1], 0, 0, 0);
    }
    __builtin_amdgcn_s_setprio(0);

    if (c16 + 1 < NC16) {
      commit(p ^ 1);     // other buffer: chunk-c readers unaffected; chunk
                         // c-1 readers finished at the previous barrier
      __syncthreads();   // one barrier per chunk
    }
  }

  const float alp = alpha[0];
  #pragma unroll
  for (int nb = 0; nb < 2; ++nb) {
    const float bs = bias[nb * 32 + lm];
    short* __restrict__ op = out + (size_t)(nb * 2 + (lm >> 4)) * PLANE16 + (lm & 15);
    #pragma unroll
    for (int r = 0; r < 16; ++r) {
      int px = w * 32 + (r & 3) + ((r >> 2) << 3) + (lh << 2);
      float v = acc[nb][r] + bs;
      v = v >= 0.f ? v : alp * v;
      op[((b * 256 + y) * 256 + px) * 16] = f2b(v);
    }
  }
}

// ---------------------------------------------------------------------------
// Weight pre-pack, c16-major (ks16 = c16*9 + tap).
// element (ks16, nblk, lane, e) =
//   W[cout = nblk*32 + lane&31][cin = c16*16 + 8*(lane>>5) + e][ky][kx]
// ---------------------------------------------------------------------------
__global__ __launch_bounds__(256)
void k_pack(const float* __restrict__ w2, const float* __restrict__ w3,
            const float* __restrict__ w4, const float* __restrict__ wf,
            short* __restrict__ wp234, short* __restrict__ wpfus)
{
  int idx = blockIdx.x * 256 + threadIdx.x;
  if (idx < 24 * 36864) {
    int conv = idx / 36864;
    int r = idx - conv * 36864;
    int which = conv >> 3, g = conv & 7;
    const float* W = (which == 0 ? w2 : which == 1 ? w3 : w4) + g * 36864;
    int ks = r >> 10;                 // [0,36) = c16*9 + t
    int nblk = (r >> 9) & 1;
    int lane = (r >> 3) & 63;
    int e = r & 7;
    int c16 = ks / 9;
    int t = ks - c16 * 9;
    int cin = c16 * 16 + ((lane >> 5) << 3) + e;
    int cout = nblk * 32 + (lane & 31);
    int ky = t / 3, kx = t % 3;
    wp234[idx] = f2b(W[((cout * 64 + cin) * 3 + ky) * 3 + kx]);
  } else {
    int idx2 = idx - 24 * 36864;
    if (idx2 >= 7 * 73728) return;
    int conv = idx2 / 73728;
    int r = idx2 - conv * 73728;
    const float* W = wf + conv * 73728;
    int ks = r >> 10;                 // [0,72)
    int nblk = (r >> 9) & 1;
    int lane = (r >> 3) & 63;
    int e = r & 7;
    int c16 = ks / 9;
    int t = ks - c16 * 9;
    int cin = c16 * 16 + ((lane >> 5) << 3) + e;
    int cout = nblk * 32 + (lane & 31);
    int ky = t / 3, kx = t % 3;
    wpfus[idx2] = f2b(W[((cout * 128 + cin) * 3 + ky) * 3 + kx]);
  }
}

// ---------------------------------------------------------------------------
// Head stage 1: sample conv (32x32, stride 32). s_all[g][b][c][gy][gx], fp32.
// ---------------------------------------------------------------------------
__global__ __launch_bounds__(256)
void k_sample(const float* __restrict__ x, const float* __restrict__ sw,
              float* __restrict__ s_all)
{
  int idx = blockIdx.x * 256 + threadIdx.x;  // 8*8*13*64 = 53248 threads
  int gx = idx & 7, gy = (idx >> 3) & 7;
  int t = idx >> 6;
  int c = t % 13; t /= 13;
  int b = t & 7, g = t >> 3;
  const float* xb = x + b * 65536 + (gy * 32) * 256 + gx * 32;
  const float* wp = sw + (g * 13 + c) * 1024;
  float acc = 0.f;
  for (int i = 0; i < 32; ++i) {
    #pragma unroll
    for (int j = 0; j < 32; ++j) acc += xb[i * 256 + j] * wp[i * 32 + j];
  }
  s_all[idx] = acc;
}

// ---------------------------------------------------------------------------
// Head stage 2: 1x1 up conv + bias, fused with depth_to_space.
// z_all[g][b][y][x] fp32, pos = (y%32)*32 + (x%32).
// ---------------------------------------------------------------------------
__global__ __launch_bounds__(256)
void k_upz(const float* __restrict__ s_all, const float* __restrict__ upw,
           const float* __restrict__ upb, float* __restrict__ z_all)
{
  int idx = blockIdx.x * 256 + threadIdx.x;  // 4194304
  int x = idx & 255, y = (idx >> 8) & 255;
  int b = (idx >> 16) & 7, g = idx >> 19;
  int pos = (y & 31) * 32 + (x & 31);
  int gy = y >> 5, gx = x >> 5;
  const float* sp = s_all + ((g * 8 + b) * 13) * 64 + gy * 8 + gx;
  const float* wp = upw + (g * 1024 + pos) * 13;
  float a = upb[g * 1024 + pos];
  #pragma unroll
  for (int c = 0; c < 13; ++c) a += wp[c] * sp[c * 64];
  z_all[idx] = a;
}

// ---------------------------------------------------------------------------
// Head stage 3: conv1 (1 -> 64, 3x3, pad 1) + PReLU, writes 16-ch planes.
// XCD-affine: b = wgid & 7 so its writes land on the XCD that fus will read.
// ---------------------------------------------------------------------------
__global__ __launch_bounds__(256)
void k_conv1(const float* __restrict__ z, const float* __restrict__ w,
             const float* __restrict__ bias, const float* __restrict__ alpha,
             short* __restrict__ out)
{
  int wg = blockIdx.x;                 // 0..2047
  int b = wg & 7;
  int y = wg >> 3;                     // 0..255
  int x = threadIdx.x;                 // 0..255
  int pid = (b * 256 + y) * 256 + x;
  float zv[9];
  #pragma unroll
  for (int t = 0; t < 9; ++t) {
    int dy = t / 3, dx = t % 3;
    int yy = y + dy - 1, xx = x + dx - 1;
    zv[t] = ((unsigned)yy < 256u && (unsigned)xx < 256u)
              ? z[b * 65536 + yy * 256 + xx] : 0.f;
  }
  float alp = alpha[0];
  #pragma unroll
  for (int c0 = 0; c0 < 64; c0 += 8) {
    short8 pack;
    #pragma unroll
    for (int e = 0; e < 8; ++e) {
      int c = c0 + e;
      float a = bias[c];
      #pragma unroll
      for (int t = 0; t < 9; ++t) a += w[c * 9 + t] * zv[t];
      a = a >= 0.f ? a : alp * a;
      pack[e] = f2b(a);
    }
    *(short8*)(out + (size_t)(c0 >> 4) * PLANE16 + pid * 16 + (c0 & 8)) = pack;
  }
}

// ---------------------------------------------------------------------------
// t5: 64 -> 1, 3x3, pad 1, + bias, fp32 output into d_out slice.
// XCD-affine b = wgid & 7: reads act produced on the same XCD.
// ---------------------------------------------------------------------------
__global__ __launch_bounds__(256)
void k_t5(const short* __restrict__ in, const float* __restrict__ w,
          const float* __restrict__ bias, float* __restrict__ out)
{
  int wg = blockIdx.x;                 // 0..2047
  int b = wg & 7;
  int y = wg >> 3;                     // 0..255
  int x = threadIdx.x;                 // 0..255
  float acc = bias[0];
  for (int dy = 0; dy < 3; ++dy) {
    int yy = y + dy - 1;
    if ((unsigned)yy >= 256u) continue;
    for (int dx = 0; dx < 3; ++dx) {
      int xx = x + dx - 1;
      if ((unsigned)xx >= 256u) continue;
      const int pix = (b * 256 + yy) * 256 + xx;
      #pragma unroll
      for (int c0 = 0; c0 < 64; c0 += 8) {
        short8 v = *(const short8*)(in + (size_t)(c0 >> 4) * PLANE16 + pix * 16 + (c0 & 8));
        #pragma unroll
        for (int e = 0; e < 8; ++e)
          acc += w[(c0 + e) * 9 + dy * 3 + dx] * b2f(v[e]);
      }
    }
  }
  out[(b * 256 + y) * 256 + x] = acc;
}

// ---------------------------------------------------------------------------
extern "C" void kernel_launch(void* const* d_in, const int* in_sizes, int n_in,
                              void* d_out, int out_size, void* d_ws, size_t ws_size,
                              hipStream_t stream) {
  const float* X   = (const float*)d_in[0];
  const float* SW  = (const float*)d_in[1];
  const float* UPW = (const float*)d_in[2];
  const float* UPB = (const float*)d_in[3];
  const float* C1W = (const float*)d_in[4];
  const float* C1B = (const float*)d_in[5];
  const float* C1A = (const float*)d_in[6];
  const float* FW  = (const float*)d_in[7];
  const float* FB  = (const float*)d_in[8];
  const float* FA  = (const float*)d_in[9];
  const float* W2  = (const float*)d_in[10];
  const float* B2  = (const float*)d_in[11];
  const float* A2  = (const float*)d_in[12];
  const float* W3  = (const float*)d_in[13];
  const float* B3  = (const float*)d_in[14];
  const float* A3  = (const float*)d_in[15];
  const float* W4  = (const float*)d_in[16];
  const float* B4  = (const float*)d_in[17];
  const float* A4  = (const float*)d_in[18];
  const float* W5  = (const float*)d_in[19];
  const float* B5  = (const float*)d_in[20];
  float* OUT = (float*)d_out;
  (void)in_sizes; (void)n_in; (void)out_size; (void)ws_size;

  uint8_t* base = (uint8_t*)d_ws;
  size_t off = 0;
  auto alloc = [&](size_t bytes) -> uint8_t* {
    uint8_t* r = base + off;
    off += (bytes + 255) & ~(size_t)255;
    return r;
  };
  const size_t ACT_ELEMS = 4ull * PLANE16;             // 33,554,432 bf16
  short* act[3];
  for (int i = 0; i < 3; ++i) act[i] = (short*)alloc(ACT_ELEMS * 2);
  float* z_all = (float*)alloc(4194304ull * 4);
  float* s_all = (float*)alloc(53248ull * 4);
  short* wp234 = (short*)alloc(884736ull * 2);
  short* wpfus = (short*)alloc(516096ull * 2);

  k_pack<<<dim3(5472), dim3(256), 0, stream>>>(W2, W3, W4, FW, wp234, wpfus);
  k_sample<<<dim3(208), dim3(256), 0, stream>>>(X, SW, s_all);
  k_upz<<<dim3(16384), dim3(256), 0, stream>>>(s_all, UPW, UPB, z_all);

  int cur = 0, A = 1, B = 2;
  // head(0) -> cur
  k_conv1<<<dim3(2048), dim3(256), 0, stream>>>(z_all, C1W, C1B, C1A, act[cur]);

  for (int m = 0; m < 8; ++m) {
    const short* wp_t2 = wp234 + (0 * 8 + m) * 36864;
    const short* wp_t3 = wp234 + (1 * 8 + m) * 36864;
    const short* wp_t4 = wp234 + (2 * 8 + m) * 36864;

    k_conv<4><<<dim3(2048), dim3(512), 0, stream>>>(
        act[cur], act[cur], wp_t2, B2 + m * 64, A2 + m, act[A]);
    k_conv<4><<<dim3(2048), dim3(512), 0, stream>>>(
        act[A], act[A], wp_t3, B3 + m * 64, A3 + m, act[B]);
    k_conv<4><<<dim3(2048), dim3(512), 0, stream>>>(
        act[B], act[B], wp_t4, B4 + m * 64, A4 + m, act[A]);
    k_t5<<<dim3(2048), dim3(256), 0, stream>>>(
        act[A], W5 + m * 576, B5 + m, OUT + (size_t)m * 524288);

    if (m < 7) {
      // head(m+1) -> act[B] (free after t4 consumed it)
      k_conv1<<<dim3(2048), dim3(256), 0, stream>>>(
          z_all + (size_t)(m + 1) * 524288, C1W + (m + 1) * 576,
          C1B + (m + 1) * 64, C1A + (m + 1), act[B]);
      // fus(cur, head) -> act[A] (free after t5 consumed it)
      k_conv<8><<<dim3(2048), dim3(512), 0, stream>>>(
          act[cur], act[B], wpfus + m * 73728, FB + m * 64, FA + m, act[A]);
      int tmp = cur; cur = A; A = tmp;  // new cur = fus output
    }
  }
}